// Round 1
// baseline (286.074 us; speedup 1.0000x reference)
//
#include <hip/hip_runtime.h>

// Encoder block: x:(4,1024,1024) f32. QKV proj -> MHA(16 heads) -> Wo -> +res -> norm(ddof=1)
// -> FF(relu) -> +res -> norm. bf16 MFMA GEMMs (threshold 0.11375 permits), fp32 norms.

typedef __bf16 bf16x8 __attribute__((ext_vector_type(8)));
typedef float f32x4 __attribute__((ext_vector_type(4)));
typedef unsigned short ushort8 __attribute__((ext_vector_type(8)));
typedef unsigned short ushort4v __attribute__((ext_vector_type(4)));

static __device__ __forceinline__ unsigned short f2bf(float f) {
  unsigned int u = __builtin_bit_cast(unsigned int, f);
  u = (u + 0x7FFFu + ((u >> 16) & 1u)) >> 16;  // RNE
  return (unsigned short)u;
}

__global__ void cvt_f32_to_bf16(const float* __restrict__ in,
                                unsigned short* __restrict__ out, int n4) {
  int i = blockIdx.x * blockDim.x + threadIdx.x;
  if (i < n4) {
    const float4 v = reinterpret_cast<const float4*>(in)[i];
    ushort4v o;
    o[0] = f2bf(v.x); o[1] = f2bf(v.y); o[2] = f2bf(v.z); o[3] = f2bf(v.w);
    reinterpret_cast<ushort4v*>(out)[i] = o;
  }
}

// C[M,N] = A[M,K] @ W[N,K]^T + bias ; optional ReLU ; out fp32 or bf16.
// 128x128 tile, BK=32, 4 waves (2x2), each wave 64x64 = 4x4 frags of 16x16x32 MFMA.
template<bool RELU, bool OUT_BF16>
__global__ __launch_bounds__(256)
void gemm_bt(const unsigned short* __restrict__ A,
             const unsigned short* __restrict__ W,
             const float* __restrict__ bias,
             void* __restrict__ Cout, int M, int N, int K) {
  __shared__ __align__(16) unsigned short Al[128][40];  // +8 pad: 2-way conflicts only
  __shared__ __align__(16) unsigned short Bl[128][40];
  const int tid = threadIdx.x;
  const int lane = tid & 63;
  const int w = tid >> 6;
  const int wr = w >> 1, wc = w & 1;
  const int grp = lane >> 4, l15 = lane & 15;
  const long bRow = (long)blockIdx.x * 128;
  const long bCol = (long)blockIdx.y * 128;
  const int sr = tid >> 2;          // staging row 0..63
  const int sc = (tid & 3) * 8;     // staging col {0,8,16,24}

  f32x4 acc[4][4];
#pragma unroll
  for (int m = 0; m < 4; m++)
#pragma unroll
    for (int n = 0; n < 4; n++) { f32x4 z = {0.f,0.f,0.f,0.f}; acc[m][n] = z; }

  const unsigned short* Ap0 = A + (bRow + sr) * (long)K + sc;
  const unsigned short* Ap1 = Ap0 + 64L * K;
  const unsigned short* Wp0 = W + (bCol + sr) * (long)K + sc;
  const unsigned short* Wp1 = Wp0 + 64L * K;

  for (int k0 = 0; k0 < K; k0 += 32) {
    ushort8 a0 = *(const ushort8*)(Ap0 + k0);
    ushort8 a1 = *(const ushort8*)(Ap1 + k0);
    ushort8 b0 = *(const ushort8*)(Wp0 + k0);
    ushort8 b1 = *(const ushort8*)(Wp1 + k0);
    __syncthreads();  // prior iter's ds_reads done before overwrite
    *(ushort8*)&Al[sr][sc] = a0;
    *(ushort8*)&Al[64 + sr][sc] = a1;
    *(ushort8*)&Bl[sr][sc] = b0;
    *(ushort8*)&Bl[64 + sr][sc] = b1;
    __syncthreads();
    bf16x8 af[4], bfr[4];
#pragma unroll
    for (int m = 0; m < 4; m++)
      af[m] = *(const bf16x8*)&Al[wr * 64 + m * 16 + l15][grp * 8];
#pragma unroll
    for (int n = 0; n < 4; n++)
      bfr[n] = *(const bf16x8*)&Bl[wc * 64 + n * 16 + l15][grp * 8];
#pragma unroll
    for (int m = 0; m < 4; m++)
#pragma unroll
      for (int n = 0; n < 4; n++)
        acc[m][n] = __builtin_amdgcn_mfma_f32_16x16x32_bf16(af[m], bfr[n], acc[m][n], 0, 0, 0);
  }

#pragma unroll
  for (int n = 0; n < 4; n++) {
    const long col = bCol + wc * 64 + n * 16 + l15;
    const float bv = bias[col];
#pragma unroll
    for (int m = 0; m < 4; m++) {
      const long row0 = bRow + wr * 64 + m * 16 + grp * 4;
#pragma unroll
      for (int r = 0; r < 4; r++) {
        float v = acc[m][n][r] + bv;
        if (RELU) v = fmaxf(v, 0.f);
        const long idx = (row0 + r) * (long)N + col;
        if (OUT_BF16) ((unsigned short*)Cout)[idx] = f2bf(v);
        else          ((float*)Cout)[idx] = v;
      }
    }
  }
}

// Flash attention: block = 64 q-rows of one (b,h); 4 waves x 16 rows. kd=64, KV tiles of 64.
__global__ __launch_bounds__(256)
void attn_kernel(const unsigned short* __restrict__ Qb,
                 const unsigned short* __restrict__ Kb,
                 const unsigned short* __restrict__ Vb,
                 const int* __restrict__ maskp,
                 unsigned short* __restrict__ Ob) {
  const int S = 1024, D = 1024;
  __shared__ __align__(16) unsigned short Kl[64][72];  // [kcol][kd], +8 pad
  __shared__ __align__(16) unsigned short Vt[64][72];  // [d][k] transposed
  __shared__ __align__(16) unsigned short Pl[64][72];  // [q][k] probs bf16
  const int tid = threadIdx.x;
  const int lane = tid & 63;
  const int w = tid >> 6;
  const int grp = lane >> 4, l15 = lane & 15;
  const int qt = blockIdx.x;
  const int b = blockIdx.y >> 4, h = blockIdx.y & 15;
  const float NEG = -__builtin_inff();

  // Q fragments stay in registers: wave's 16 q-rows
  const unsigned short* Qp = Qb + ((size_t)(b * S + qt * 64 + w * 16 + l15)) * D + h * 64;
  const bf16x8 aq0 = *(const bf16x8*)(Qp + grp * 8);
  const bf16x8 aq1 = *(const bf16x8*)(Qp + 32 + grp * 8);

  f32x4 acc_o[4];
#pragma unroll
  for (int f = 0; f < 4; f++) { f32x4 z = {0.f,0.f,0.f,0.f}; acc_o[f] = z; }
  float m_run[4] = {NEG, NEG, NEG, NEG};
  float l_run[4] = {0.f, 0.f, 0.f, 0.f};

  const int sr0 = tid >> 3;          // 0..31
  const int sc0 = (tid & 7) * 8;     // 0..56

  for (int kt = 0; kt < 16; ++kt) {
    const int kbase = kt * 64;
    const unsigned short* Kp = Kb + ((size_t)(b * S + kbase + sr0)) * D + h * 64 + sc0;
    const unsigned short* Vp = Vb + ((size_t)(b * S + kbase + sr0)) * D + h * 64 + sc0;
    ushort8 kv0 = *(const ushort8*)Kp;
    ushort8 kv1 = *(const ushort8*)(Kp + 32 * (size_t)D);
    ushort8 vv0 = *(const ushort8*)Vp;
    ushort8 vv1 = *(const ushort8*)(Vp + 32 * (size_t)D);
    __syncthreads();  // prior iter's Kl/Vt/Pl reads complete
    *(ushort8*)&Kl[sr0][sc0] = kv0;
    *(ushort8*)&Kl[32 + sr0][sc0] = kv1;
#pragma unroll
    for (int j = 0; j < 8; j++) {
      Vt[sc0 + j][sr0] = vv0[j];
      Vt[sc0 + j][32 + sr0] = vv1[j];
    }
    __syncthreads();  // staging visible

    // S = Q K^T (scaled later); wave computes 16q x 64k
    f32x4 sfr[4];
#pragma unroll
    for (int f = 0; f < 4; f++) {
      bf16x8 bk0 = *(const bf16x8*)&Kl[f * 16 + l15][grp * 8];
      bf16x8 bk1 = *(const bf16x8*)&Kl[f * 16 + l15][32 + grp * 8];
      f32x4 z = {0.f,0.f,0.f,0.f};
      z = __builtin_amdgcn_mfma_f32_16x16x32_bf16(aq0, bk0, z, 0, 0, 0);
      z = __builtin_amdgcn_mfma_f32_16x16x32_bf16(aq1, bk1, z, 0, 0, 0);
      sfr[f] = z;
    }
#pragma unroll
    for (int f = 0; f < 4; f++) {
      const int col = kbase + f * 16 + l15;
      const bool live = maskp[b * S + col] != 0;
#pragma unroll
      for (int r = 0; r < 4; r++)
        sfr[f][r] = live ? sfr[f][r] * 0.125f : NEG;
    }
    // online softmax; row r of lane-group grp -> q-row grp*4+r (16 lanes hold 16 cols x 4 frags)
#pragma unroll
    for (int r = 0; r < 4; r++) {
      float rm = fmaxf(fmaxf(sfr[0][r], sfr[1][r]), fmaxf(sfr[2][r], sfr[3][r]));
      rm = fmaxf(rm, __shfl_xor(rm, 1));
      rm = fmaxf(rm, __shfl_xor(rm, 2));
      rm = fmaxf(rm, __shfl_xor(rm, 4));
      rm = fmaxf(rm, __shfl_xor(rm, 8));
      const float mn = fmaxf(m_run[r], rm);
      const float scale = __expf(m_run[r] - mn);  // first iter: exp(-inf)=0
      m_run[r] = mn;
      float rs = 0.f;
#pragma unroll
      for (int f = 0; f < 4; f++) {
        const float p = __expf(sfr[f][r] - mn);
        rs += p;
        Pl[w * 16 + grp * 4 + r][f * 16 + l15] = f2bf(p);
        acc_o[f][r] *= scale;
      }
      rs += __shfl_xor(rs, 1);
      rs += __shfl_xor(rs, 2);
      rs += __shfl_xor(rs, 4);
      rs += __shfl_xor(rs, 8);
      l_run[r] = l_run[r] * scale + rs;
    }
    __syncthreads();  // Pl visible

    // O += P V
    const bf16x8 ap0 = *(const bf16x8*)&Pl[w * 16 + l15][grp * 8];
    const bf16x8 ap1 = *(const bf16x8*)&Pl[w * 16 + l15][32 + grp * 8];
#pragma unroll
    for (int f = 0; f < 4; f++) {
      bf16x8 bv0 = *(const bf16x8*)&Vt[f * 16 + l15][grp * 8];
      bf16x8 bv1 = *(const bf16x8*)&Vt[f * 16 + l15][32 + grp * 8];
      acc_o[f] = __builtin_amdgcn_mfma_f32_16x16x32_bf16(ap0, bv0, acc_o[f], 0, 0, 0);
      acc_o[f] = __builtin_amdgcn_mfma_f32_16x16x32_bf16(ap1, bv1, acc_o[f], 0, 0, 0);
    }
  }

#pragma unroll
  for (int f = 0; f < 4; f++)
#pragma unroll
    for (int r = 0; r < 4; r++) {
      const float v = acc_o[f][r] / l_run[r];
      const int row = qt * 64 + w * 16 + grp * 4 + r;
      Ob[((size_t)(b * S + row)) * D + h * 64 + f * 16 + l15] = f2bf(v);
    }
}

// out = alpha*( (a+b - mean) / (std_ddof1 + eps) ) + beta ; optional bf16 copy
template<bool BF16OUT>
__global__ __launch_bounds__(256)
void norm_residual(const float* __restrict__ a, const float* __restrict__ bsrc,
                   const float* __restrict__ alpha, const float* __restrict__ beta,
                   float* __restrict__ out, unsigned short* __restrict__ out_bf) {
  const int D = 1024;
  const size_t base = (size_t)blockIdx.x * D + threadIdx.x * 4;
  const float4 va = *(const float4*)(a + base);
  const float4 vb = *(const float4*)(bsrc + base);
  const float x0 = va.x + vb.x, x1 = va.y + vb.y, x2 = va.z + vb.z, x3 = va.w + vb.w;
  float s1 = x0 + x1 + x2 + x3;
  float s2 = x0 * x0 + x1 * x1 + x2 * x2 + x3 * x3;
#pragma unroll
  for (int m = 1; m < 64; m <<= 1) {
    s1 += __shfl_xor(s1, m);
    s2 += __shfl_xor(s2, m);
  }
  __shared__ float red[8];
  const int w = threadIdx.x >> 6, lane = threadIdx.x & 63;
  if (lane == 0) { red[w] = s1; red[4 + w] = s2; }
  __syncthreads();
  s1 = red[0] + red[1] + red[2] + red[3];
  s2 = red[4] + red[5] + red[6] + red[7];
  const float mean = s1 * (1.f / 1024.f);
  const float var = fmaxf((s2 - 1024.f * mean * mean) * (1.f / 1023.f), 0.f);
  const float k = alpha[0] / (sqrtf(var) + 1e-6f);
  const float b0 = beta[0];
  const float y0 = (x0 - mean) * k + b0;
  const float y1 = (x1 - mean) * k + b0;
  const float y2 = (x2 - mean) * k + b0;
  const float y3 = (x3 - mean) * k + b0;
  float4 o = {y0, y1, y2, y3};
  *(float4*)(out + base) = o;
  if (BF16OUT) {
    ushort4v ob;
    ob[0] = f2bf(y0); ob[1] = f2bf(y1); ob[2] = f2bf(y2); ob[3] = f2bf(y3);
    *(ushort4v*)(out_bf + base) = ob;
  }
}

extern "C" void kernel_launch(void* const* d_in, const int* in_sizes, int n_in,
                              void* d_out, int out_size, void* d_ws, size_t ws_size,
                              hipStream_t stream) {
  const float* x      = (const float*)d_in[0];
  const int*   maskp  = (const int*)d_in[1];
  const float* Wq_w   = (const float*)d_in[2];
  const float* Wq_b   = (const float*)d_in[3];
  const float* Wk_w   = (const float*)d_in[4];
  const float* Wk_b   = (const float*)d_in[5];
  const float* Wv_w   = (const float*)d_in[6];
  const float* Wv_b   = (const float*)d_in[7];
  const float* Wo_w   = (const float*)d_in[8];
  const float* Wo_b   = (const float*)d_in[9];
  const float* W1_w   = (const float*)d_in[10];
  const float* W1_b   = (const float*)d_in[11];
  const float* W2_w   = (const float*)d_in[12];
  const float* W2_b   = (const float*)d_in[13];
  const float* alpha1 = (const float*)d_in[14];
  const float* beta1  = (const float*)d_in[15];
  const float* alpha2 = (const float*)d_in[16];
  const float* beta2  = (const float*)d_in[17];

  const int B = 4, S = 1024, D = 1024;
  const int M = B * S;  // 4096
  const size_t MiB = 1u << 20;
  char* ws = (char*)d_ws;
  // workspace layout (peak 84 MiB, with dead-buffer reuse)
  unsigned short* x_bf   = (unsigned short*)(ws + 0 * MiB);   // 8 MiB
  unsigned short* Wq_bf  = (unsigned short*)(ws + 8 * MiB);   // 2 MiB each
  unsigned short* Wk_bf  = (unsigned short*)(ws + 10 * MiB);
  unsigned short* Wv_bf  = (unsigned short*)(ws + 12 * MiB);
  unsigned short* Wo_bf  = (unsigned short*)(ws + 14 * MiB);
  unsigned short* W1_bf  = (unsigned short*)(ws + 16 * MiB);
  unsigned short* W2_bf  = (unsigned short*)(ws + 18 * MiB);
  unsigned short* Q_bf   = (unsigned short*)(ws + 20 * MiB);  // 8 MiB
  unsigned short* K_bf   = (unsigned short*)(ws + 28 * MiB);  // 8 MiB
  unsigned short* V_bf   = (unsigned short*)(ws + 36 * MiB);  // 8 MiB
  unsigned short* O_bf   = (unsigned short*)(ws + 44 * MiB);  // 8 MiB
  float*          attnpr = (float*)(ws + 52 * MiB);           // 16 MiB
  float*          x1buf  = (float*)(ws + 68 * MiB);           // 16 MiB
  unsigned short* x1_bf  = (unsigned short*)(ws + 20 * MiB);  // reuse Q (dead)
  unsigned short* ff1_bf = (unsigned short*)(ws + 28 * MiB);  // reuse K (dead)
  float*          ff2buf = (float*)(ws + 36 * MiB);           // reuse V+O (dead)

  auto cvt = [&](const float* src, unsigned short* dst, int n) {
    cvt_f32_to_bf16<<<dim3((n / 4 + 255) / 256), dim3(256), 0, stream>>>(src, dst, n / 4);
  };
  cvt(x, x_bf, M * D);
  cvt(Wq_w, Wq_bf, D * D);
  cvt(Wk_w, Wk_bf, D * D);
  cvt(Wv_w, Wv_bf, D * D);
  cvt(Wo_w, Wo_bf, D * D);
  cvt(W1_w, W1_bf, D * D);
  cvt(W2_w, W2_bf, D * D);

  dim3 gg(M / 128, D / 128);  // 32 x 8
  gemm_bt<false, true><<<gg, dim3(256), 0, stream>>>(x_bf, Wq_bf, Wq_b, Q_bf, M, D, D);
  gemm_bt<false, true><<<gg, dim3(256), 0, stream>>>(x_bf, Wk_bf, Wk_b, K_bf, M, D, D);
  gemm_bt<false, true><<<gg, dim3(256), 0, stream>>>(x_bf, Wv_bf, Wv_b, V_bf, M, D, D);

  attn_kernel<<<dim3(S / 64, B * 16), dim3(256), 0, stream>>>(Q_bf, K_bf, V_bf, maskp, O_bf);

  gemm_bt<false, false><<<gg, dim3(256), 0, stream>>>(O_bf, Wo_bf, Wo_b, attnpr, M, D, D);
  norm_residual<true><<<dim3(M), dim3(256), 0, stream>>>(x, attnpr, alpha1, beta1, x1buf, x1_bf);
  gemm_bt<true, true><<<gg, dim3(256), 0, stream>>>(x1_bf, W1_bf, W1_b, ff1_bf, M, D, D);
  gemm_bt<false, false><<<gg, dim3(256), 0, stream>>>(ff1_bf, W2_bf, W2_b, ff2buf, M, D, D);
  norm_residual<false><<<dim3(M), dim3(256), 0, stream>>>(x1buf, ff2buf, alpha2, beta2,
                                                          (float*)d_out, nullptr);
}

// Round 2
// 261.977 us; speedup vs baseline: 1.0920x; 1.0920x over previous
//
#include <hip/hip_runtime.h>

// Encoder block: x:(4,1024,1024) f32. QKV proj -> MHA(16 heads) -> Wo -> +res -> norm(ddof=1)
// -> FF(relu) -> +res -> norm. bf16 MFMA GEMMs (threshold 0.11375 permits), fp32 norms.
// R2: GEMMs use global_load_lds width=16 (m97 structure); V written pre-transposed by its
// GEMM epilogue so attention stages V^T with conflict-free vector writes.

typedef __bf16 bf16x8 __attribute__((ext_vector_type(8)));
typedef float f32x4 __attribute__((ext_vector_type(4)));
typedef unsigned short ushort8 __attribute__((ext_vector_type(8)));
typedef unsigned short ushort4v __attribute__((ext_vector_type(4)));

static __device__ __forceinline__ unsigned short f2bf(float f) {
  unsigned int u = __builtin_bit_cast(unsigned int, f);
  u = (u + 0x7FFFu + ((u >> 16) & 1u)) >> 16;  // RNE
  return (unsigned short)u;
}

static __device__ __forceinline__ void gload_lds16(const void* g, void* l) {
  __builtin_amdgcn_global_load_lds(
      (const __attribute__((address_space(1))) unsigned int*)g,
      (__attribute__((address_space(3))) unsigned int*)l, 16, 0, 0);
}

__global__ void cvt_f32_to_bf16(const float* __restrict__ in,
                                unsigned short* __restrict__ out, int n4) {
  int i = blockIdx.x * blockDim.x + threadIdx.x;
  if (i < n4) {
    const float4 v = reinterpret_cast<const float4*>(in)[i];
    ushort4v o;
    o[0] = f2bf(v.x); o[1] = f2bf(v.y); o[2] = f2bf(v.z); o[3] = f2bf(v.w);
    reinterpret_cast<ushort4v*>(out)[i] = o;
  }
}

// C[M,N] = A[M,K] @ W[N,K]^T + bias ; optional ReLU.
// OUT_MODE: 0 = f32 row-major, 1 = bf16 row-major, 2 = bf16 V-transposed [(b*16+h)][d][s]
// m97 structure: 128x128 tile, BK=32, unpadded LDS, global_load_lds dwordx4, 2 barriers/step.
template<bool RELU, int OUT_MODE>
__global__ __launch_bounds__(256)
void gemm_bt(const unsigned short* __restrict__ A,
             const unsigned short* __restrict__ W,
             const float* __restrict__ bias,
             void* __restrict__ Cout, int M, int N, int K) {
  __shared__ __align__(16) unsigned short Al[128][32];  // unpadded: linear for gload_lds
  __shared__ __align__(16) unsigned short Bl[128][32];
  const int tid = threadIdx.x;
  const int lane = tid & 63;
  const int w = tid >> 6;
  const int wr = w >> 1, wc = w & 1;
  const int grp = lane >> 4, l15 = lane & 15;
  const long bRow = (long)blockIdx.x * 128;
  const long bCol = (long)blockIdx.y * 128;

  f32x4 acc[4][4];
#pragma unroll
  for (int m = 0; m < 4; m++)
#pragma unroll
    for (int n = 0; n < 4; n++) { f32x4 z = {0.f,0.f,0.f,0.f}; acc[m][n] = z; }

  // staging: LDS byte off = round*4096 + tid*16  <=> row = round*64 + tid/4, col = (tid&3)*8
  const int srow = tid >> 2;         // 0..63
  const int scol = (tid & 3) * 8;
  const unsigned short* Ag0 = A + (bRow + srow) * (long)K + scol;
  const unsigned short* Ag1 = Ag0 + 64L * K;
  const unsigned short* Wg0 = W + (bCol + srow) * (long)K + scol;
  const unsigned short* Wg1 = Wg0 + 64L * K;
  unsigned short* ldsA = &Al[0][0] + w * 512;  // wave-uniform base (w*1024 bytes)
  unsigned short* ldsB = &Bl[0][0] + w * 512;

  for (int k0 = 0; k0 < K; k0 += 32) {
    __syncthreads();  // prior iter's ds_reads done before overwrite
    gload_lds16(Ag0 + k0, ldsA);
    gload_lds16(Ag1 + k0, ldsA + 2048);
    gload_lds16(Wg0 + k0, ldsB);
    gload_lds16(Wg1 + k0, ldsB + 2048);
    __syncthreads();  // vmcnt drained by barrier -> tiles resident
    bf16x8 af[4], bfr[4];
#pragma unroll
    for (int m = 0; m < 4; m++)
      af[m] = *(const bf16x8*)&Al[wr * 64 + m * 16 + l15][grp * 8];
#pragma unroll
    for (int n = 0; n < 4; n++)
      bfr[n] = *(const bf16x8*)&Bl[wc * 64 + n * 16 + l15][grp * 8];
#pragma unroll
    for (int m = 0; m < 4; m++)
#pragma unroll
      for (int n = 0; n < 4; n++)
        acc[m][n] = __builtin_amdgcn_mfma_f32_16x16x32_bf16(af[m], bfr[n], acc[m][n], 0, 0, 0);
  }

#pragma unroll
  for (int n = 0; n < 4; n++) {
    const long col = bCol + wc * 64 + n * 16 + l15;
    const float bv = bias[col];
#pragma unroll
    for (int m = 0; m < 4; m++) {
      const long row0 = bRow + wr * 64 + m * 16 + grp * 4;
#pragma unroll
      for (int r = 0; r < 4; r++) {
        float v = acc[m][n][r] + bv;
        if (RELU) v = fmaxf(v, 0.f);
        const long row = row0 + r;
        if (OUT_MODE == 0) {
          ((float*)Cout)[row * (long)N + col] = v;
        } else if (OUT_MODE == 1) {
          ((unsigned short*)Cout)[row * (long)N + col] = f2bf(v);
        } else {  // V^T: [(b*16+h)][d=col&63][s=row&1023]
          const long idx = (((row >> 10) * 16 + (col >> 6)) << 16) + ((col & 63) << 10) + (row & 1023);
          ((unsigned short*)Cout)[idx] = f2bf(v);
        }
      }
    }
  }
}

// Flash attention: block = 64 q-rows of one (b,h); 4 waves x 16 rows. kd=64, KV tiles of 64.
// V arrives pre-transposed: Vt_g[(b*16+h)][d=64][s=1024].
__global__ __launch_bounds__(256)
void attn_kernel(const unsigned short* __restrict__ Qb,
                 const unsigned short* __restrict__ Kb,
                 const unsigned short* __restrict__ Vt_g,
                 const int* __restrict__ maskp,
                 unsigned short* __restrict__ Ob) {
  const int S = 1024, D = 1024;
  __shared__ __align__(16) unsigned short Kl[64][72];  // [kcol][kd], +8 pad
  __shared__ __align__(16) unsigned short Vl[64][72];  // [d][k]
  __shared__ __align__(16) unsigned short Pl[64][72];  // [q][k] probs bf16
  const int tid = threadIdx.x;
  const int lane = tid & 63;
  const int w = tid >> 6;
  const int grp = lane >> 4, l15 = lane & 15;
  const int qt = blockIdx.x;
  const int b = blockIdx.y >> 4, h = blockIdx.y & 15;
  const float NEG = -__builtin_inff();

  // Q fragments stay in registers: wave's 16 q-rows
  const unsigned short* Qp = Qb + ((size_t)(b * S + qt * 64 + w * 16 + l15)) * D + h * 64;
  const bf16x8 aq0 = *(const bf16x8*)(Qp + grp * 8);
  const bf16x8 aq1 = *(const bf16x8*)(Qp + 32 + grp * 8);
  const unsigned short* Vg = Vt_g + ((size_t)(b * 16 + h) << 16);

  f32x4 acc_o[4];
#pragma unroll
  for (int f = 0; f < 4; f++) { f32x4 z = {0.f,0.f,0.f,0.f}; acc_o[f] = z; }
  float m_run[4] = {NEG, NEG, NEG, NEG};
  float l_run[4] = {0.f, 0.f, 0.f, 0.f};

  const int sr0 = tid >> 3;          // 0..31
  const int sc0 = (tid & 7) * 8;     // 0..56

  for (int kt = 0; kt < 16; ++kt) {
    const int kbase = kt * 64;
    const unsigned short* Kp = Kb + ((size_t)(b * S + kbase + sr0)) * D + h * 64 + sc0;
    ushort8 kv0 = *(const ushort8*)Kp;
    ushort8 kv1 = *(const ushort8*)(Kp + 32 * (size_t)D);
    const unsigned short* Vp = Vg + (size_t)sr0 * S + kbase + sc0;
    ushort8 vv0 = *(const ushort8*)Vp;
    ushort8 vv1 = *(const ushort8*)(Vp + 32 * (size_t)S);
    __syncthreads();  // prior iter's Kl/Vl/Pl reads complete
    *(ushort8*)&Kl[sr0][sc0] = kv0;
    *(ushort8*)&Kl[32 + sr0][sc0] = kv1;
    *(ushort8*)&Vl[sr0][sc0] = vv0;      // row d=sr0, cols k
    *(ushort8*)&Vl[32 + sr0][sc0] = vv1;
    __syncthreads();  // staging visible

    // S = Q K^T; wave computes 16q x 64k
    f32x4 sfr[4];
#pragma unroll
    for (int f = 0; f < 4; f++) {
      bf16x8 bk0 = *(const bf16x8*)&Kl[f * 16 + l15][grp * 8];
      bf16x8 bk1 = *(const bf16x8*)&Kl[f * 16 + l15][32 + grp * 8];
      f32x4 z = {0.f,0.f,0.f,0.f};
      z = __builtin_amdgcn_mfma_f32_16x16x32_bf16(aq0, bk0, z, 0, 0, 0);
      z = __builtin_amdgcn_mfma_f32_16x16x32_bf16(aq1, bk1, z, 0, 0, 0);
      sfr[f] = z;
    }
#pragma unroll
    for (int f = 0; f < 4; f++) {
      const int col = kbase + f * 16 + l15;
      const bool live = maskp[b * S + col] != 0;
#pragma unroll
      for (int r = 0; r < 4; r++)
        sfr[f][r] = live ? sfr[f][r] * 0.125f : NEG;
    }
    // online softmax; row r of lane-group grp -> q-row grp*4+r
#pragma unroll
    for (int r = 0; r < 4; r++) {
      float rm = fmaxf(fmaxf(sfr[0][r], sfr[1][r]), fmaxf(sfr[2][r], sfr[3][r]));
      rm = fmaxf(rm, __shfl_xor(rm, 1));
      rm = fmaxf(rm, __shfl_xor(rm, 2));
      rm = fmaxf(rm, __shfl_xor(rm, 4));
      rm = fmaxf(rm, __shfl_xor(rm, 8));
      const float mn = fmaxf(m_run[r], rm);
      const float scale = __expf(m_run[r] - mn);  // first iter: exp(-inf)=0
      m_run[r] = mn;
      float rs = 0.f;
#pragma unroll
      for (int f = 0; f < 4; f++) {
        const float p = __expf(sfr[f][r] - mn);
        rs += p;
        Pl[w * 16 + grp * 4 + r][f * 16 + l15] = f2bf(p);
        acc_o[f][r] *= scale;
      }
      rs += __shfl_xor(rs, 1);
      rs += __shfl_xor(rs, 2);
      rs += __shfl_xor(rs, 4);
      rs += __shfl_xor(rs, 8);
      l_run[r] = l_run[r] * scale + rs;
    }
    __syncthreads();  // Pl visible

    // O += P V
    const bf16x8 ap0 = *(const bf16x8*)&Pl[w * 16 + l15][grp * 8];
    const bf16x8 ap1 = *(const bf16x8*)&Pl[w * 16 + l15][32 + grp * 8];
#pragma unroll
    for (int f = 0; f < 4; f++) {
      bf16x8 bv0 = *(const bf16x8*)&Vl[f * 16 + l15][grp * 8];
      bf16x8 bv1 = *(const bf16x8*)&Vl[f * 16 + l15][32 + grp * 8];
      acc_o[f] = __builtin_amdgcn_mfma_f32_16x16x32_bf16(ap0, bv0, acc_o[f], 0, 0, 0);
      acc_o[f] = __builtin_amdgcn_mfma_f32_16x16x32_bf16(ap1, bv1, acc_o[f], 0, 0, 0);
    }
  }

#pragma unroll
  for (int f = 0; f < 4; f++)
#pragma unroll
    for (int r = 0; r < 4; r++) {
      const float v = acc_o[f][r] / l_run[r];
      const int row = qt * 64 + w * 16 + grp * 4 + r;
      Ob[((size_t)(b * S + row)) * D + h * 64 + f * 16 + l15] = f2bf(v);
    }
}

// out = alpha*( (a+b - mean) / (std_ddof1 + eps) ) + beta ; optional bf16 copy
template<bool BF16OUT>
__global__ __launch_bounds__(256)
void norm_residual(const float* __restrict__ a, const float* __restrict__ bsrc,
                   const float* __restrict__ alpha, const float* __restrict__ beta,
                   float* __restrict__ out, unsigned short* __restrict__ out_bf) {
  const int D = 1024;
  const size_t base = (size_t)blockIdx.x * D + threadIdx.x * 4;
  const float4 va = *(const float4*)(a + base);
  const float4 vb = *(const float4*)(bsrc + base);
  const float x0 = va.x + vb.x, x1 = va.y + vb.y, x2 = va.z + vb.z, x3 = va.w + vb.w;
  float s1 = x0 + x1 + x2 + x3;
  float s2 = x0 * x0 + x1 * x1 + x2 * x2 + x3 * x3;
#pragma unroll
  for (int m = 1; m < 64; m <<= 1) {
    s1 += __shfl_xor(s1, m);
    s2 += __shfl_xor(s2, m);
  }
  __shared__ float red[8];
  const int w = threadIdx.x >> 6, lane = threadIdx.x & 63;
  if (lane == 0) { red[w] = s1; red[4 + w] = s2; }
  __syncthreads();
  s1 = red[0] + red[1] + red[2] + red[3];
  s2 = red[4] + red[5] + red[6] + red[7];
  const float mean = s1 * (1.f / 1024.f);
  const float var = fmaxf((s2 - 1024.f * mean * mean) * (1.f / 1023.f), 0.f);
  const float k = alpha[0] / (sqrtf(var) + 1e-6f);
  const float b0 = beta[0];
  const float y0 = (x0 - mean) * k + b0;
  const float y1 = (x1 - mean) * k + b0;
  const float y2 = (x2 - mean) * k + b0;
  const float y3 = (x3 - mean) * k + b0;
  float4 o = {y0, y1, y2, y3};
  *(float4*)(out + base) = o;
  if (BF16OUT) {
    ushort4v ob;
    ob[0] = f2bf(y0); ob[1] = f2bf(y1); ob[2] = f2bf(y2); ob[3] = f2bf(y3);
    *(ushort4v*)(out_bf + base) = ob;
  }
}

extern "C" void kernel_launch(void* const* d_in, const int* in_sizes, int n_in,
                              void* d_out, int out_size, void* d_ws, size_t ws_size,
                              hipStream_t stream) {
  const float* x      = (const float*)d_in[0];
  const int*   maskp  = (const int*)d_in[1];
  const float* Wq_w   = (const float*)d_in[2];
  const float* Wq_b   = (const float*)d_in[3];
  const float* Wk_w   = (const float*)d_in[4];
  const float* Wk_b   = (const float*)d_in[5];
  const float* Wv_w   = (const float*)d_in[6];
  const float* Wv_b   = (const float*)d_in[7];
  const float* Wo_w   = (const float*)d_in[8];
  const float* Wo_b   = (const float*)d_in[9];
  const float* W1_w   = (const float*)d_in[10];
  const float* W1_b   = (const float*)d_in[11];
  const float* W2_w   = (const float*)d_in[12];
  const float* W2_b   = (const float*)d_in[13];
  const float* alpha1 = (const float*)d_in[14];
  const float* beta1  = (const float*)d_in[15];
  const float* alpha2 = (const float*)d_in[16];
  const float* beta2  = (const float*)d_in[17];

  const int B = 4, S = 1024, D = 1024;
  const int M = B * S;  // 4096
  const size_t MiB = 1u << 20;
  char* ws = (char*)d_ws;
  unsigned short* x_bf   = (unsigned short*)(ws + 0 * MiB);   // 8 MiB
  unsigned short* Wq_bf  = (unsigned short*)(ws + 8 * MiB);   // 2 MiB each
  unsigned short* Wk_bf  = (unsigned short*)(ws + 10 * MiB);
  unsigned short* Wv_bf  = (unsigned short*)(ws + 12 * MiB);
  unsigned short* Wo_bf  = (unsigned short*)(ws + 14 * MiB);
  unsigned short* W1_bf  = (unsigned short*)(ws + 16 * MiB);
  unsigned short* W2_bf  = (unsigned short*)(ws + 18 * MiB);
  unsigned short* Q_bf   = (unsigned short*)(ws + 20 * MiB);  // 8 MiB
  unsigned short* K_bf   = (unsigned short*)(ws + 28 * MiB);  // 8 MiB
  unsigned short* Vt_bf  = (unsigned short*)(ws + 36 * MiB);  // 8 MiB (pre-transposed V)
  unsigned short* O_bf   = (unsigned short*)(ws + 44 * MiB);  // 8 MiB
  float*          attnpr = (float*)(ws + 52 * MiB);           // 16 MiB
  float*          x1buf  = (float*)(ws + 68 * MiB);           // 16 MiB
  unsigned short* x1_bf  = (unsigned short*)(ws + 20 * MiB);  // reuse Q (dead)
  unsigned short* ff1_bf = (unsigned short*)(ws + 28 * MiB);  // reuse K (dead)
  float*          ff2buf = (float*)(ws + 36 * MiB);           // reuse V+O (dead)

  auto cvt = [&](const float* src, unsigned short* dst, int n) {
    cvt_f32_to_bf16<<<dim3((n / 4 + 255) / 256), dim3(256), 0, stream>>>(src, dst, n / 4);
  };
  cvt(x, x_bf, M * D);
  cvt(Wq_w, Wq_bf, D * D);
  cvt(Wk_w, Wk_bf, D * D);
  cvt(Wv_w, Wv_bf, D * D);
  cvt(Wo_w, Wo_bf, D * D);
  cvt(W1_w, W1_bf, D * D);
  cvt(W2_w, W2_bf, D * D);

  dim3 gg(M / 128, D / 128);  // 32 x 8
  gemm_bt<false, 1><<<gg, dim3(256), 0, stream>>>(x_bf, Wq_bf, Wq_b, Q_bf, M, D, D);
  gemm_bt<false, 1><<<gg, dim3(256), 0, stream>>>(x_bf, Wk_bf, Wk_b, K_bf, M, D, D);
  gemm_bt<false, 2><<<gg, dim3(256), 0, stream>>>(x_bf, Wv_bf, Wv_b, Vt_bf, M, D, D);

  attn_kernel<<<dim3(S / 64, B * 16), dim3(256), 0, stream>>>(Q_bf, K_bf, Vt_bf, maskp, O_bf);

  gemm_bt<false, 0><<<gg, dim3(256), 0, stream>>>(O_bf, Wo_bf, Wo_b, attnpr, M, D, D);
  norm_residual<true><<<dim3(M), dim3(256), 0, stream>>>(x, attnpr, alpha1, beta1, x1buf, x1_bf);
  gemm_bt<true, 1><<<gg, dim3(256), 0, stream>>>(x1_bf, W1_bf, W1_b, ff1_bf, M, D, D);
  gemm_bt<false, 0><<<gg, dim3(256), 0, stream>>>(ff1_bf, W2_bf, W2_b, ff2buf, M, D, D);
  norm_residual<false><<<dim3(M), dim3(256), 0, stream>>>(x1buf, ff2buf, alpha2, beta2,
                                                          (float*)d_out, nullptr);
}

// Round 3
// 203.041 us; speedup vs baseline: 1.4089x; 1.2903x over previous
//
#include <hip/hip_runtime.h>

// Encoder block: x:(4,1024,1024) f32. Fused-QKV proj -> MHA(16 heads) -> Wo -> +res -> norm
// (ddof=1) -> FF(relu) -> +res -> norm. bf16 MFMA GEMMs, fp32 norms.
// R3: BM=64/BN=128/BK=64 GEMM (>=2 blocks/CU), XOR-swizzled LDS (pre-swizzled global src +
// linear global_load_lds dest + swizzled ds_read), fused QKV (6 blocks/CU), swizzled attn.

typedef __bf16 bf16x8 __attribute__((ext_vector_type(8)));
typedef float f32x4 __attribute__((ext_vector_type(4)));
typedef unsigned short ushort4v __attribute__((ext_vector_type(4)));

static __device__ __forceinline__ unsigned short f2bf(float f) {
  return __builtin_bit_cast(unsigned short, (__bf16)f);  // HW RNE cvt
}

static __device__ __forceinline__ void gload_lds16(const void* g, void* l) {
  __builtin_amdgcn_global_load_lds(
      (const __attribute__((address_space(1))) unsigned int*)g,
      (__attribute__((address_space(3))) unsigned int*)l, 16, 0, 0);
}

// One launch: y=0..3 -> x quarters; y=4..6 -> Wq/Wk/Wv into concat; y=7..9 -> Wo/W1/W2.
__global__ __launch_bounds__(256)
void cvt_all(const float* __restrict__ x, const float* __restrict__ wq,
             const float* __restrict__ wk, const float* __restrict__ wv,
             const float* __restrict__ wo, const float* __restrict__ w1,
             const float* __restrict__ w2,
             unsigned short* __restrict__ x_bf, unsigned short* __restrict__ wqkv_bf,
             unsigned short* __restrict__ wo_bf, unsigned short* __restrict__ w1_bf,
             unsigned short* __restrict__ w2_bf) {
  const int y = blockIdx.y;
  const size_t MEL = 1u << 20;
  const float* src;
  unsigned short* dst;
  switch (y) {
    case 0: case 1: case 2: case 3: src = x + y * MEL; dst = x_bf + y * MEL; break;
    case 4: src = wq; dst = wqkv_bf; break;
    case 5: src = wk; dst = wqkv_bf + MEL; break;
    case 6: src = wv; dst = wqkv_bf + 2 * MEL; break;
    case 7: src = wo; dst = wo_bf; break;
    case 8: src = w1; dst = w1_bf; break;
    default: src = w2; dst = w2_bf; break;
  }
  const int i = blockIdx.x * 256 + threadIdx.x;
  const float4 v = reinterpret_cast<const float4*>(src)[i];
  ushort4v o;
  o[0] = f2bf(v.x); o[1] = f2bf(v.y); o[2] = f2bf(v.z); o[3] = f2bf(v.w);
  reinterpret_cast<ushort4v*>(dst)[i] = o;
}

// C[M,N] = A[M,K] @ W[N,K]^T + bias. BM=64, BN=128, BK=64, 4 waves (2x2), wave tile 32x64.
// LDS content XOR-swizzled: chunk(row, c) holds global k-chunk c^(row&7) (16B chunks).
// OUT_MODE: 0 = f32 row-major; 1 = bf16 row-major; 2 = fused QKV split (seg = bCol>>10:
//   0 -> Q bf16 rm, 1 -> K bf16 rm, 2 -> V transposed [(b*16+h)][d=64][s=1024]).
template<bool RELU, int OUT_MODE>
__global__ __launch_bounds__(256, 2)
void gemm_bt(const unsigned short* __restrict__ A,
             const unsigned short* __restrict__ W,
             const float* __restrict__ bias0, const float* __restrict__ bias1,
             const float* __restrict__ bias2,
             void* __restrict__ out0, unsigned short* __restrict__ outK,
             unsigned short* __restrict__ outVt, int M, int N, int K) {
  __shared__ __align__(16) unsigned short Al[64][64];    // 8 KiB
  __shared__ __align__(16) unsigned short Bl[128][64];   // 16 KiB
  const int tid = threadIdx.x;
  const int lane = tid & 63;
  const int w = tid >> 6;
  const int wr = w >> 1, wc = w & 1;
  const int grp = lane >> 4, l15 = lane & 15;
  const long bRow = (long)blockIdx.x * 64;
  const long bCol = (long)blockIdx.y * 128;

  f32x4 acc[2][4];
#pragma unroll
  for (int m = 0; m < 2; m++)
#pragma unroll
    for (int n = 0; n < 4; n++) { f32x4 z = {0.f,0.f,0.f,0.f}; acc[m][n] = z; }

  // staging: thread t covers LDS chunk t (+256/round); row = rd*32 + t>>3, pos = t&7.
  // source k-chunk = pos ^ (row&7); (row+32)&7 == row&7 so XOR is round-invariant.
  const int srow = tid >> 3;                    // 0..31
  const int xc = (((tid & 7) ^ (srow & 7)) << 3);
  const unsigned short* Ag0 = A + (bRow + srow) * (long)K + xc;
  const unsigned short* Ag1 = Ag0 + 32L * K;
  const unsigned short* Wg0 = W + (bCol + srow) * (long)K + xc;
  const unsigned short* Wg1 = Wg0 + 32L * K;
  const unsigned short* Wg2 = Wg0 + 64L * K;
  const unsigned short* Wg3 = Wg0 + 96L * K;
  unsigned short* ldsA = &Al[0][0] + w * 512;   // wave-uniform base, +2048/round
  unsigned short* ldsB = &Bl[0][0] + w * 512;

  for (int k0 = 0; k0 < K; k0 += 64) {
    __syncthreads();  // prior iter's ds_reads done before overwrite
    gload_lds16(Ag0 + k0, ldsA);
    gload_lds16(Ag1 + k0, ldsA + 2048);
    gload_lds16(Wg0 + k0, ldsB);
    gload_lds16(Wg1 + k0, ldsB + 2048);
    gload_lds16(Wg2 + k0, ldsB + 4096);
    gload_lds16(Wg3 + k0, ldsB + 6144);
    __syncthreads();  // barrier drains vmcnt -> tiles resident
#pragma unroll
    for (int kk = 0; kk < 2; kk++) {
      bf16x8 af[2], bf[4];
#pragma unroll
      for (int m = 0; m < 2; m++) {
        const int R = wr * 32 + m * 16 + l15;
        const int pos = (kk * 4 + grp) ^ (R & 7);
        af[m] = *(const bf16x8*)&Al[R][pos << 3];
      }
#pragma unroll
      for (int n = 0; n < 4; n++) {
        const int R = wc * 64 + n * 16 + l15;
        const int pos = (kk * 4 + grp) ^ (R & 7);
        bf[n] = *(const bf16x8*)&Bl[R][pos << 3];
      }
#pragma unroll
      for (int m = 0; m < 2; m++)
#pragma unroll
        for (int n = 0; n < 4; n++)
          acc[m][n] = __builtin_amdgcn_mfma_f32_16x16x32_bf16(af[m], bf[n], acc[m][n], 0, 0, 0);
    }
  }

  const int seg = (OUT_MODE == 2) ? (int)(bCol >> 10) : 0;
  const float* bp = (OUT_MODE == 2) ? (seg == 0 ? bias0 : seg == 1 ? bias1 : bias2) : bias0;
#pragma unroll
  for (int n = 0; n < 4; n++) {
    const long col = bCol + wc * 64 + n * 16 + l15;
    const float bv = bp[OUT_MODE == 2 ? (col & 1023) : col];
#pragma unroll
    for (int m = 0; m < 2; m++) {
      const long row0 = bRow + wr * 32 + m * 16 + grp * 4;
#pragma unroll
      for (int r = 0; r < 4; r++) {
        float v = acc[m][n][r] + bv;
        if (RELU) v = fmaxf(v, 0.f);
        const long row = row0 + r;
        if (OUT_MODE == 0) {
          ((float*)out0)[row * (long)N + col] = v;
        } else if (OUT_MODE == 1) {
          ((unsigned short*)out0)[row * (long)N + col] = f2bf(v);
        } else {
          if (seg == 0) {
            ((unsigned short*)out0)[row * 1024 + col] = f2bf(v);
          } else if (seg == 1) {
            outK[row * 1024 + (col & 1023)] = f2bf(v);
          } else {
            const long vc = col & 1023;
            const long idx = (((row >> 10) * 16 + (vc >> 6)) << 16) + ((vc & 63) << 10) + (row & 1023);
            outVt[idx] = f2bf(v);
          }
        }
      }
    }
  }
}

// Flash attention: block = 64 q-rows of one (b,h); 4 waves x 16 rows. kd=64, KV tiles of 64.
// V pre-transposed: Vt_g[(b*16+h)][d=64][s=1024]. K/V staged via global_load_lds with
// pre-swizzled source; Kl/Vl/Pl are unpadded [64][64] with chunk XOR (row&7) swizzle.
__global__ __launch_bounds__(256)
void attn_kernel(const unsigned short* __restrict__ Qb,
                 const unsigned short* __restrict__ Kb,
                 const unsigned short* __restrict__ Vt_g,
                 const int* __restrict__ maskp,
                 unsigned short* __restrict__ Ob) {
  const int S = 1024, D = 1024;
  __shared__ __align__(16) unsigned short Kl[64][64];
  __shared__ __align__(16) unsigned short Vl[64][64];
  __shared__ __align__(16) unsigned short Pl[64][64];
  const int tid = threadIdx.x;
  const int lane = tid & 63;
  const int w = tid >> 6;
  const int grp = lane >> 4, l15 = lane & 15;
  const int qt = blockIdx.x;
  const int b = blockIdx.y >> 4, h = blockIdx.y & 15;
  const float NEG = -__builtin_inff();
  const float SCL = 0.125f * 1.44269504088896340736f;  // 1/sqrt(64) * log2(e)

  const unsigned short* Qp = Qb + ((size_t)(b * S + qt * 64 + w * 16 + l15)) * D + h * 64;
  const bf16x8 aq0 = *(const bf16x8*)(Qp + grp * 8);
  const bf16x8 aq1 = *(const bf16x8*)(Qp + 32 + grp * 8);

  f32x4 acc_o[4];
#pragma unroll
  for (int f = 0; f < 4; f++) { f32x4 z = {0.f,0.f,0.f,0.f}; acc_o[f] = z; }
  float m_run[4] = {NEG, NEG, NEG, NEG};
  float l_run[4] = {0.f, 0.f, 0.f, 0.f};

  // staging geometry (same as gemm): row = rd*32 + tid>>3, source chunk = (tid&7)^(row&7)
  const int srow = tid >> 3;
  const int xc = (((tid & 7) ^ (srow & 7)) << 3);
  const unsigned short* Kg0 = Kb + ((size_t)(b * S + srow)) * D + h * 64 + xc;
  const unsigned short* Kg1 = Kg0 + 32 * (size_t)D;
  const unsigned short* Vgb = Vt_g + (((size_t)(b * 16 + h)) << 16);
  const unsigned short* Vg0 = Vgb + (size_t)srow * S + xc;
  const unsigned short* Vg1 = Vg0 + 32 * (size_t)S;
  unsigned short* ldsK = &Kl[0][0] + w * 512;
  unsigned short* ldsV = &Vl[0][0] + w * 512;

  for (int kt = 0; kt < 16; ++kt) {
    const int kbase = kt * 64;
    __syncthreads();  // prior iter's Kl/Vl/Pl reads complete
    gload_lds16(Kg0 + (size_t)kbase * D, ldsK);
    gload_lds16(Kg1 + (size_t)kbase * D, ldsK + 2048);
    gload_lds16(Vg0 + kbase, ldsV);
    gload_lds16(Vg1 + kbase, ldsV + 2048);
    __syncthreads();  // tiles resident

    // S2 = (Q K^T) * 0.125 * log2e  (log2-domain softmax)
    f32x4 sfr[4];
#pragma unroll
    for (int f = 0; f < 4; f++) {
      const int R = f * 16 + l15;
      const int p0 = (grp ^ (R & 7)) << 3;
      const int p1 = ((4 + grp) ^ (R & 7)) << 3;
      bf16x8 bk0 = *(const bf16x8*)&Kl[R][p0];
      bf16x8 bk1 = *(const bf16x8*)&Kl[R][p1];
      f32x4 z = {0.f,0.f,0.f,0.f};
      z = __builtin_amdgcn_mfma_f32_16x16x32_bf16(aq0, bk0, z, 0, 0, 0);
      z = __builtin_amdgcn_mfma_f32_16x16x32_bf16(aq1, bk1, z, 0, 0, 0);
      sfr[f] = z;
    }
#pragma unroll
    for (int f = 0; f < 4; f++) {
      const bool live = maskp[b * S + kbase + f * 16 + l15] != 0;
#pragma unroll
      for (int r = 0; r < 4; r++)
        sfr[f][r] = live ? sfr[f][r] * SCL : NEG;
    }
#pragma unroll
    for (int r = 0; r < 4; r++) {
      float rm = fmaxf(fmaxf(sfr[0][r], sfr[1][r]), fmaxf(sfr[2][r], sfr[3][r]));
      rm = fmaxf(rm, __shfl_xor(rm, 1));
      rm = fmaxf(rm, __shfl_xor(rm, 2));
      rm = fmaxf(rm, __shfl_xor(rm, 4));
      rm = fmaxf(rm, __shfl_xor(rm, 8));
      const float mn = fmaxf(m_run[r], rm);
      const float scale = exp2f(m_run[r] - mn);  // first iter: exp2(-inf)=0
      m_run[r] = mn;
      const int q = w * 16 + grp * 4 + r;
      float rs = 0.f;
#pragma unroll
      for (int f = 0; f < 4; f++) {
        const float p = exp2f(sfr[f][r] - mn);
        rs += p;
        const int cchunk = (f * 2 + (l15 >> 3)) ^ (q & 7);
        ((unsigned short*)Pl)[q * 64 + (cchunk << 3) + (l15 & 7)] = f2bf(p);
        acc_o[f][r] *= scale;
      }
      rs += __shfl_xor(rs, 1);
      rs += __shfl_xor(rs, 2);
      rs += __shfl_xor(rs, 4);
      rs += __shfl_xor(rs, 8);
      l_run[r] = l_run[r] * scale + rs;
    }
    __syncthreads();  // Pl visible

    // O += P V
    const int Rp = w * 16 + l15;
    const bf16x8 ap0 = *(const bf16x8*)&Pl[Rp][((grp ^ (Rp & 7)) << 3)];
    const bf16x8 ap1 = *(const bf16x8*)&Pl[Rp][(((4 + grp) ^ (Rp & 7)) << 3)];
#pragma unroll
    for (int f = 0; f < 4; f++) {
      const int Rv = f * 16 + l15;
      bf16x8 bv0 = *(const bf16x8*)&Vl[Rv][((grp ^ (Rv & 7)) << 3)];
      bf16x8 bv1 = *(const bf16x8*)&Vl[Rv][(((4 + grp) ^ (Rv & 7)) << 3)];
      acc_o[f] = __builtin_amdgcn_mfma_f32_16x16x32_bf16(ap0, bv0, acc_o[f], 0, 0, 0);
      acc_o[f] = __builtin_amdgcn_mfma_f32_16x16x32_bf16(ap1, bv1, acc_o[f], 0, 0, 0);
    }
  }

#pragma unroll
  for (int f = 0; f < 4; f++)
#pragma unroll
    for (int r = 0; r < 4; r++) {
      const float v = acc_o[f][r] / l_run[r];
      const int row = qt * 64 + w * 16 + grp * 4 + r;
      Ob[((size_t)(b * S + row)) * D + h * 64 + f * 16 + l15] = f2bf(v);
    }
}

// out = alpha*( (a+b - mean) / (std_ddof1 + eps) ) + beta ; optional bf16 copy
template<bool BF16OUT>
__global__ __launch_bounds__(256)
void norm_residual(const float* __restrict__ a, const float* __restrict__ bsrc,
                   const float* __restrict__ alpha, const float* __restrict__ beta,
                   float* __restrict__ out, unsigned short* __restrict__ out_bf) {
  const int D = 1024;
  const size_t base = (size_t)blockIdx.x * D + threadIdx.x * 4;
  const float4 va = *(const float4*)(a + base);
  const float4 vb = *(const float4*)(bsrc + base);
  const float x0 = va.x + vb.x, x1 = va.y + vb.y, x2 = va.z + vb.z, x3 = va.w + vb.w;
  float s1 = x0 + x1 + x2 + x3;
  float s2 = x0 * x0 + x1 * x1 + x2 * x2 + x3 * x3;
#pragma unroll
  for (int m = 1; m < 64; m <<= 1) {
    s1 += __shfl_xor(s1, m);
    s2 += __shfl_xor(s2, m);
  }
  __shared__ float red[8];
  const int w = threadIdx.x >> 6, lane = threadIdx.x & 63;
  if (lane == 0) { red[w] = s1; red[4 + w] = s2; }
  __syncthreads();
  s1 = red[0] + red[1] + red[2] + red[3];
  s2 = red[4] + red[5] + red[6] + red[7];
  const float mean = s1 * (1.f / 1024.f);
  const float var = fmaxf((s2 - 1024.f * mean * mean) * (1.f / 1023.f), 0.f);
  const float k = alpha[0] / (sqrtf(var) + 1e-6f);
  const float b0 = beta[0];
  const float y0 = (x0 - mean) * k + b0;
  const float y1 = (x1 - mean) * k + b0;
  const float y2 = (x2 - mean) * k + b0;
  const float y3 = (x3 - mean) * k + b0;
  float4 o = {y0, y1, y2, y3};
  *(float4*)(out + base) = o;
  if (BF16OUT) {
    ushort4v ob;
    ob[0] = f2bf(y0); ob[1] = f2bf(y1); ob[2] = f2bf(y2); ob[3] = f2bf(y3);
    *(ushort4v*)(out_bf + base) = ob;
  }
}

extern "C" void kernel_launch(void* const* d_in, const int* in_sizes, int n_in,
                              void* d_out, int out_size, void* d_ws, size_t ws_size,
                              hipStream_t stream) {
  const float* x      = (const float*)d_in[0];
  const int*   maskp  = (const int*)d_in[1];
  const float* Wq_w   = (const float*)d_in[2];
  const float* Wq_b   = (const float*)d_in[3];
  const float* Wk_w   = (const float*)d_in[4];
  const float* Wk_b   = (const float*)d_in[5];
  const float* Wv_w   = (const float*)d_in[6];
  const float* Wv_b   = (const float*)d_in[7];
  const float* Wo_w   = (const float*)d_in[8];
  const float* Wo_b   = (const float*)d_in[9];
  const float* W1_w   = (const float*)d_in[10];
  const float* W1_b   = (const float*)d_in[11];
  const float* W2_w   = (const float*)d_in[12];
  const float* W2_b   = (const float*)d_in[13];
  const float* alpha1 = (const float*)d_in[14];
  const float* beta1  = (const float*)d_in[15];
  const float* alpha2 = (const float*)d_in[16];
  const float* beta2  = (const float*)d_in[17];

  const int B = 4, S = 1024, D = 1024;
  const int M = B * S;  // 4096
  const size_t MiB = 1u << 20;
  char* ws = (char*)d_ws;
  unsigned short* x_bf    = (unsigned short*)(ws + 0 * MiB);   // 8 MiB
  unsigned short* Wqkv_bf = (unsigned short*)(ws + 8 * MiB);   // 6 MiB (Wq|Wk|Wv rows)
  unsigned short* Wo_bf   = (unsigned short*)(ws + 14 * MiB);  // 2 MiB
  unsigned short* W1_bf   = (unsigned short*)(ws + 16 * MiB);
  unsigned short* W2_bf   = (unsigned short*)(ws + 18 * MiB);
  unsigned short* Q_bf    = (unsigned short*)(ws + 20 * MiB);  // 8 MiB
  unsigned short* K_bf    = (unsigned short*)(ws + 28 * MiB);  // 8 MiB
  unsigned short* Vt_bf   = (unsigned short*)(ws + 36 * MiB);  // 8 MiB (pre-transposed V)
  unsigned short* O_bf    = (unsigned short*)(ws + 44 * MiB);  // 8 MiB
  float*          attnpr  = (float*)(ws + 52 * MiB);           // 16 MiB
  float*          x1buf   = (float*)(ws + 68 * MiB);           // 16 MiB
  unsigned short* x1_bf   = (unsigned short*)(ws + 20 * MiB);  // reuse Q (dead)
  unsigned short* ff1_bf  = (unsigned short*)(ws + 28 * MiB);  // reuse K (dead)
  float*          ff2buf  = (float*)(ws + 36 * MiB);           // reuse V+O (dead)

  cvt_all<<<dim3(1024, 10), dim3(256), 0, stream>>>(
      x, Wq_w, Wk_w, Wv_w, Wo_w, W1_w, W2_w, x_bf, Wqkv_bf, Wo_bf, W1_bf, W2_bf);

  // fused QKV: C[4096,3072]; seg0->Q rm, seg1->K rm, seg2->V transposed
  gemm_bt<false, 2><<<dim3(M / 64, 24), dim3(256), 0, stream>>>(
      x_bf, Wqkv_bf, Wq_b, Wk_b, Wv_b, Q_bf, K_bf, Vt_bf, M, 3072, D);

  attn_kernel<<<dim3(S / 64, B * 16), dim3(256), 0, stream>>>(Q_bf, K_bf, Vt_bf, maskp, O_bf);

  gemm_bt<false, 0><<<dim3(M / 64, 8), dim3(256), 0, stream>>>(
      O_bf, Wo_bf, Wo_b, nullptr, nullptr, attnpr, nullptr, nullptr, M, D, D);
  norm_residual<true><<<dim3(M), dim3(256), 0, stream>>>(x, attnpr, alpha1, beta1, x1buf, x1_bf);
  gemm_bt<true, 1><<<dim3(M / 64, 8), dim3(256), 0, stream>>>(
      x1_bf, W1_bf, W1_b, nullptr, nullptr, ff1_bf, nullptr, nullptr, M, D, D);
  gemm_bt<false, 0><<<dim3(M / 64, 8), dim3(256), 0, stream>>>(
      ff1_bf, W2_bf, W2_b, nullptr, nullptr, ff2buf, nullptr, nullptr, M, D, D);
  norm_residual<false><<<dim3(M), dim3(256), 0, stream>>>(x1buf, ff2buf, alpha2, beta2,
                                                          (float*)d_out, nullptr);
}

// Round 4
// 196.745 us; speedup vs baseline: 1.4540x; 1.0320x over previous
//
#include <hip/hip_runtime.h>

// Encoder block: x:(4,1024,1024) f32. Fused-QKV proj -> MHA(16 heads) -> Wo -> +res -> norm
// (ddof=1) -> FF(relu) -> +res -> norm. bf16 MFMA GEMMs, fp32 norms.
// R4: attn rewritten: ones-MFMA row-sums, wave-uniform deferred max (THR=8), mask as fma
// bias, double-buffered K/V with early-issue global_load_lds, XCD-local grid, setprio.

typedef __bf16 bf16x8 __attribute__((ext_vector_type(8)));
typedef float f32x4 __attribute__((ext_vector_type(4)));
typedef unsigned short ushort4v __attribute__((ext_vector_type(4)));

static __device__ __forceinline__ unsigned short f2bf(float f) {
  return __builtin_bit_cast(unsigned short, (__bf16)f);  // HW RNE cvt
}

static __device__ __forceinline__ void gload_lds16(const void* g, void* l) {
  __builtin_amdgcn_global_load_lds(
      (const __attribute__((address_space(1))) unsigned int*)g,
      (__attribute__((address_space(3))) unsigned int*)l, 16, 0, 0);
}

// One launch: y=0..3 -> x quarters; y=4..6 -> Wq/Wk/Wv into concat; y=7..9 -> Wo/W1/W2.
__global__ __launch_bounds__(256)
void cvt_all(const float* __restrict__ x, const float* __restrict__ wq,
             const float* __restrict__ wk, const float* __restrict__ wv,
             const float* __restrict__ wo, const float* __restrict__ w1,
             const float* __restrict__ w2,
             unsigned short* __restrict__ x_bf, unsigned short* __restrict__ wqkv_bf,
             unsigned short* __restrict__ wo_bf, unsigned short* __restrict__ w1_bf,
             unsigned short* __restrict__ w2_bf) {
  const int y = blockIdx.y;
  const size_t MEL = 1u << 20;
  const float* src;
  unsigned short* dst;
  switch (y) {
    case 0: case 1: case 2: case 3: src = x + y * MEL; dst = x_bf + y * MEL; break;
    case 4: src = wq; dst = wqkv_bf; break;
    case 5: src = wk; dst = wqkv_bf + MEL; break;
    case 6: src = wv; dst = wqkv_bf + 2 * MEL; break;
    case 7: src = wo; dst = wo_bf; break;
    case 8: src = w1; dst = w1_bf; break;
    default: src = w2; dst = w2_bf; break;
  }
  const int i = blockIdx.x * 256 + threadIdx.x;
  const float4 v = reinterpret_cast<const float4*>(src)[i];
  ushort4v o;
  o[0] = f2bf(v.x); o[1] = f2bf(v.y); o[2] = f2bf(v.z); o[3] = f2bf(v.w);
  reinterpret_cast<ushort4v*>(dst)[i] = o;
}

// C[M,N] = A[M,K] @ W[N,K]^T + bias. BM=64, BN=128, BK=64, 4 waves (2x2), wave tile 32x64.
// LDS content XOR-swizzled: chunk(row, c) holds global k-chunk c^(row&7) (16B chunks).
// OUT_MODE: 0 = f32 row-major; 1 = bf16 row-major; 2 = fused QKV split (seg = bCol>>10:
//   0 -> Q bf16 rm, 1 -> K bf16 rm, 2 -> V transposed [(b*16+h)][d=64][s=1024]).
template<bool RELU, int OUT_MODE>
__global__ __launch_bounds__(256, 2)
void gemm_bt(const unsigned short* __restrict__ A,
             const unsigned short* __restrict__ W,
             const float* __restrict__ bias0, const float* __restrict__ bias1,
             const float* __restrict__ bias2,
             void* __restrict__ out0, unsigned short* __restrict__ outK,
             unsigned short* __restrict__ outVt, int M, int N, int K) {
  __shared__ __align__(16) unsigned short Al[64][64];    // 8 KiB
  __shared__ __align__(16) unsigned short Bl[128][64];   // 16 KiB
  const int tid = threadIdx.x;
  const int lane = tid & 63;
  const int w = tid >> 6;
  const int wr = w >> 1, wc = w & 1;
  const int grp = lane >> 4, l15 = lane & 15;
  const long bRow = (long)blockIdx.x * 64;
  const long bCol = (long)blockIdx.y * 128;

  f32x4 acc[2][4];
#pragma unroll
  for (int m = 0; m < 2; m++)
#pragma unroll
    for (int n = 0; n < 4; n++) { f32x4 z = {0.f,0.f,0.f,0.f}; acc[m][n] = z; }

  const int srow = tid >> 3;                    // 0..31
  const int xc = (((tid & 7) ^ (srow & 7)) << 3);
  const unsigned short* Ag0 = A + (bRow + srow) * (long)K + xc;
  const unsigned short* Ag1 = Ag0 + 32L * K;
  const unsigned short* Wg0 = W + (bCol + srow) * (long)K + xc;
  const unsigned short* Wg1 = Wg0 + 32L * K;
  const unsigned short* Wg2 = Wg0 + 64L * K;
  const unsigned short* Wg3 = Wg0 + 96L * K;
  unsigned short* ldsA = &Al[0][0] + w * 512;   // wave-uniform base
  unsigned short* ldsB = &Bl[0][0] + w * 512;

  for (int k0 = 0; k0 < K; k0 += 64) {
    __syncthreads();
    gload_lds16(Ag0 + k0, ldsA);
    gload_lds16(Ag1 + k0, ldsA + 2048);
    gload_lds16(Wg0 + k0, ldsB);
    gload_lds16(Wg1 + k0, ldsB + 2048);
    gload_lds16(Wg2 + k0, ldsB + 4096);
    gload_lds16(Wg3 + k0, ldsB + 6144);
    __syncthreads();
#pragma unroll
    for (int kk = 0; kk < 2; kk++) {
      bf16x8 af[2], bf[4];
#pragma unroll
      for (int m = 0; m < 2; m++) {
        const int R = wr * 32 + m * 16 + l15;
        const int pos = (kk * 4 + grp) ^ (R & 7);
        af[m] = *(const bf16x8*)&Al[R][pos << 3];
      }
#pragma unroll
      for (int n = 0; n < 4; n++) {
        const int R = wc * 64 + n * 16 + l15;
        const int pos = (kk * 4 + grp) ^ (R & 7);
        bf[n] = *(const bf16x8*)&Bl[R][pos << 3];
      }
#pragma unroll
      for (int m = 0; m < 2; m++)
#pragma unroll
        for (int n = 0; n < 4; n++)
          acc[m][n] = __builtin_amdgcn_mfma_f32_16x16x32_bf16(af[m], bf[n], acc[m][n], 0, 0, 0);
    }
  }

  const int seg = (OUT_MODE == 2) ? (int)(bCol >> 10) : 0;
  const float* bp = (OUT_MODE == 2) ? (seg == 0 ? bias0 : seg == 1 ? bias1 : bias2) : bias0;
#pragma unroll
  for (int n = 0; n < 4; n++) {
    const long col = bCol + wc * 64 + n * 16 + l15;
    const float bv = bp[OUT_MODE == 2 ? (col & 1023) : col];
#pragma unroll
    for (int m = 0; m < 2; m++) {
      const long row0 = bRow + wr * 32 + m * 16 + grp * 4;
#pragma unroll
      for (int r = 0; r < 4; r++) {
        float v = acc[m][n][r] + bv;
        if (RELU) v = fmaxf(v, 0.f);
        const long row = row0 + r;
        if (OUT_MODE == 0) {
          ((float*)out0)[row * (long)N + col] = v;
        } else if (OUT_MODE == 1) {
          ((unsigned short*)out0)[row * (long)N + col] = f2bf(v);
        } else {
          if (seg == 0) {
            ((unsigned short*)out0)[row * 1024 + col] = f2bf(v);
          } else if (seg == 1) {
            outK[row * 1024 + (col & 1023)] = f2bf(v);
          } else {
            const long vc = col & 1023;
            const long idx = (((row >> 10) * 16 + (vc >> 6)) << 16) + ((vc & 63) << 10) + (row & 1023);
            outVt[idx] = f2bf(v);
          }
        }
      }
    }
  }
}

// Flash attention. Grid (bh=64, qt=16): qt-blocks of one head land on one XCD (L2-local K/V).
// Block = 64 q-rows; 4 waves x 16 rows; KV tiles of 64, double-buffered.
// Softmax: wave-uniform deferred max (THR=8), row-sums l via ones-MFMA.
__global__ __launch_bounds__(256)
void attn_kernel(const unsigned short* __restrict__ Qb,
                 const unsigned short* __restrict__ Kb,
                 const unsigned short* __restrict__ Vt_g,
                 const int* __restrict__ maskp,
                 unsigned short* __restrict__ Ob) {
  const int S = 1024, D = 1024;
  __shared__ __align__(16) unsigned short Kl[2][64][64];
  __shared__ __align__(16) unsigned short Vl[2][64][64];
  __shared__ __align__(16) unsigned short Pl[64][64];
  const int tid = threadIdx.x;
  const int lane = tid & 63;
  const int w = tid >> 6;
  const int grp = lane >> 4, l15 = lane & 15;
  const int bh = blockIdx.x;                  // b*16 + h
  const int qt = blockIdx.y;
  const int b = bh >> 4, h = bh & 15;
  const float NEG = -__builtin_inff();
  const float SCL = 0.125f * 1.44269504088896340736f;  // 1/sqrt(64) * log2(e)

  const unsigned short* Qp = Qb + ((size_t)(b * S + qt * 64 + w * 16 + l15)) * D + h * 64;
  const bf16x8 aq0 = *(const bf16x8*)(Qp + grp * 8);
  const bf16x8 aq1 = *(const bf16x8*)(Qp + 32 + grp * 8);

  bf16x8 onesb;
#pragma unroll
  for (int j = 0; j < 8; j++) onesb[j] = (__bf16)1.0f;

  f32x4 acc_o[4];
#pragma unroll
  for (int f = 0; f < 4; f++) { f32x4 z = {0.f,0.f,0.f,0.f}; acc_o[f] = z; }
  f32x4 acc_l = {0.f, 0.f, 0.f, 0.f};
  float M = NEG;  // wave-uniform running max

  // staging geometry: row = rd*32 + tid>>3, source chunk = (tid&7)^(row&7)
  const int srow = tid >> 3;
  const int xc = (((tid & 7) ^ (srow & 7)) << 3);
  const unsigned short* Kg0 = Kb + ((size_t)(b * S + srow)) * D + h * 64 + xc;
  const unsigned short* Kg1 = Kg0 + 32 * (size_t)D;
  const unsigned short* Vgb = Vt_g + (((size_t)bh) << 16);
  const unsigned short* Vg0 = Vgb + (size_t)srow * S + xc;
  const unsigned short* Vg1 = Vg0 + 32 * (size_t)S;

  auto stage = [&](int kt2, int buf) {
    const size_t kb = (size_t)kt2 * 64;
    gload_lds16(Kg0 + kb * D, &Kl[buf][0][0] + w * 512);
    gload_lds16(Kg1 + kb * D, &Kl[buf][0][0] + w * 512 + 2048);
    gload_lds16(Vg0 + kb,     &Vl[buf][0][0] + w * 512);
    gload_lds16(Vg1 + kb,     &Vl[buf][0][0] + w * 512 + 2048);
  };
  stage(0, 0);  // prologue

  for (int kt = 0; kt < 16; ++kt) {
    const int cur = kt & 1;
    const int kbase = kt * 64;
    __syncthreads();  // B0: staged 'cur' complete; prev PV's Pl reads done
    if (kt < 15) stage(kt + 1, cur ^ 1);  // in flight across QK^T + softmax

    // S2 = Q K^T (bias+scale applied below)
    f32x4 sfr[4];
    __builtin_amdgcn_s_setprio(1);
#pragma unroll
    for (int f = 0; f < 4; f++) {
      const int R = f * 16 + l15;
      const int p0 = (grp ^ (R & 7)) << 3;
      const int p1 = ((4 + grp) ^ (R & 7)) << 3;
      bf16x8 bk0 = *(const bf16x8*)&Kl[cur][R][p0];
      bf16x8 bk1 = *(const bf16x8*)&Kl[cur][R][p1];
      f32x4 z = {0.f,0.f,0.f,0.f};
      z = __builtin_amdgcn_mfma_f32_16x16x32_bf16(aq0, bk0, z, 0, 0, 0);
      z = __builtin_amdgcn_mfma_f32_16x16x32_bf16(aq1, bk1, z, 0, 0, 0);
      sfr[f] = z;
    }
    __builtin_amdgcn_s_setprio(0);

    // mask as additive bias, scale via fma
#pragma unroll
    for (int f = 0; f < 4; f++) {
      const float biasf = maskp[b * S + kbase + f * 16 + l15] ? 0.f : NEG;
#pragma unroll
      for (int r = 0; r < 4; r++)
        sfr[f][r] = fmaf(sfr[f][r], SCL, biasf);
    }

    // wave-uniform deferred max
    float rm = sfr[0][0];
#pragma unroll
    for (int f = 0; f < 4; f++)
#pragma unroll
      for (int r = 0; r < 4; r++) rm = fmaxf(rm, sfr[f][r]);
    rm = fmaxf(rm, __shfl_xor(rm, 1));
    rm = fmaxf(rm, __shfl_xor(rm, 2));
    rm = fmaxf(rm, __shfl_xor(rm, 4));
    rm = fmaxf(rm, __shfl_xor(rm, 8));
    rm = fmaxf(rm, __shfl_xor(rm, 16));
    rm = fmaxf(rm, __shfl_xor(rm, 32));
    if (rm > M + 8.f) {          // wave-uniform branch; first tile: always (M=-inf)
      const float sc = exp2f(M - rm);  // first tile: 0
      M = rm;
#pragma unroll
      for (int f = 0; f < 4; f++) acc_o[f] *= sc;
      acc_l *= sc;
    }

    // P = exp2(S2 - M), bf16, swizzled store to Pl
#pragma unroll
    for (int f = 0; f < 4; f++) {
#pragma unroll
      for (int r = 0; r < 4; r++) {
        const float p = exp2f(sfr[f][r] - M);
        const int q = w * 16 + grp * 4 + r;
        const int cchunk = (f * 2 + (l15 >> 3)) ^ (q & 7);
        ((unsigned short*)Pl)[q * 64 + (cchunk << 3) + (l15 & 7)] = f2bf(p);
      }
    }
    __syncthreads();  // B1: Pl visible (also drains next-tile staging, issued early)

    // O += P V ; l += P . 1  (ones-MFMA row-sums)
    const int Rp = w * 16 + l15;
    const bf16x8 ap0 = *(const bf16x8*)&Pl[Rp][((grp ^ (Rp & 7)) << 3)];
    const bf16x8 ap1 = *(const bf16x8*)&Pl[Rp][(((4 + grp) ^ (Rp & 7)) << 3)];
    __builtin_amdgcn_s_setprio(1);
#pragma unroll
    for (int f = 0; f < 4; f++) {
      const int Rv = f * 16 + l15;
      bf16x8 bv0 = *(const bf16x8*)&Vl[cur][Rv][((grp ^ (Rv & 7)) << 3)];
      bf16x8 bv1 = *(const bf16x8*)&Vl[cur][Rv][(((4 + grp) ^ (Rv & 7)) << 3)];
      acc_o[f] = __builtin_amdgcn_mfma_f32_16x16x32_bf16(ap0, bv0, acc_o[f], 0, 0, 0);
      acc_o[f] = __builtin_amdgcn_mfma_f32_16x16x32_bf16(ap1, bv1, acc_o[f], 0, 0, 0);
    }
    acc_l = __builtin_amdgcn_mfma_f32_16x16x32_bf16(ap0, onesb, acc_l, 0, 0, 0);
    acc_l = __builtin_amdgcn_mfma_f32_16x16x32_bf16(ap1, onesb, acc_l, 0, 0, 0);
    __builtin_amdgcn_s_setprio(0);
  }

#pragma unroll
  for (int r = 0; r < 4; r++) {
    const float inv = 1.f / acc_l[r];
    const int row = qt * 64 + w * 16 + grp * 4 + r;
#pragma unroll
    for (int f = 0; f < 4; f++) {
      const float v = acc_o[f][r] * inv;
      Ob[((size_t)(b * S + row)) * D + h * 64 + f * 16 + l15] = f2bf(v);
    }
  }
}

// out = alpha*( (a+b - mean) / (std_ddof1 + eps) ) + beta ; optional bf16 copy
template<bool BF16OUT>
__global__ __launch_bounds__(256)
void norm_residual(const float* __restrict__ a, const float* __restrict__ bsrc,
                   const float* __restrict__ alpha, const float* __restrict__ beta,
                   float* __restrict__ out, unsigned short* __restrict__ out_bf) {
  const int D = 1024;
  const size_t base = (size_t)blockIdx.x * D + threadIdx.x * 4;
  const float4 va = *(const float4*)(a + base);
  const float4 vb = *(const float4*)(bsrc + base);
  const float x0 = va.x + vb.x, x1 = va.y + vb.y, x2 = va.z + vb.z, x3 = va.w + vb.w;
  float s1 = x0 + x1 + x2 + x3;
  float s2 = x0 * x0 + x1 * x1 + x2 * x2 + x3 * x3;
#pragma unroll
  for (int m = 1; m < 64; m <<= 1) {
    s1 += __shfl_xor(s1, m);
    s2 += __shfl_xor(s2, m);
  }
  __shared__ float red[8];
  const int w = threadIdx.x >> 6, lane = threadIdx.x & 63;
  if (lane == 0) { red[w] = s1; red[4 + w] = s2; }
  __syncthreads();
  s1 = red[0] + red[1] + red[2] + red[3];
  s2 = red[4] + red[5] + red[6] + red[7];
  const float mean = s1 * (1.f / 1024.f);
  const float var = fmaxf((s2 - 1024.f * mean * mean) * (1.f / 1023.f), 0.f);
  const float k = alpha[0] / (sqrtf(var) + 1e-6f);
  const float b0 = beta[0];
  const float y0 = (x0 - mean) * k + b0;
  const float y1 = (x1 - mean) * k + b0;
  const float y2 = (x2 - mean) * k + b0;
  const float y3 = (x3 - mean) * k + b0;
  float4 o = {y0, y1, y2, y3};
  *(float4*)(out + base) = o;
  if (BF16OUT) {
    ushort4v ob;
    ob[0] = f2bf(y0); ob[1] = f2bf(y1); ob[2] = f2bf(y2); ob[3] = f2bf(y3);
    *(ushort4v*)(out_bf + base) = ob;
  }
}

extern "C" void kernel_launch(void* const* d_in, const int* in_sizes, int n_in,
                              void* d_out, int out_size, void* d_ws, size_t ws_size,
                              hipStream_t stream) {
  const float* x      = (const float*)d_in[0];
  const int*   maskp  = (const int*)d_in[1];
  const float* Wq_w   = (const float*)d_in[2];
  const float* Wq_b   = (const float*)d_in[3];
  const float* Wk_w   = (const float*)d_in[4];
  const float* Wk_b   = (const float*)d_in[5];
  const float* Wv_w   = (const float*)d_in[6];
  const float* Wv_b   = (const float*)d_in[7];
  const float* Wo_w   = (const float*)d_in[8];
  const float* Wo_b   = (const float*)d_in[9];
  const float* W1_w   = (const float*)d_in[10];
  const float* W1_b   = (const float*)d_in[11];
  const float* W2_w   = (const float*)d_in[12];
  const float* W2_b   = (const float*)d_in[13];
  const float* alpha1 = (const float*)d_in[14];
  const float* beta1  = (const float*)d_in[15];
  const float* alpha2 = (const float*)d_in[16];
  const float* beta2  = (const float*)d_in[17];

  const int B = 4, S = 1024, D = 1024;
  const int M = B * S;  // 4096
  const size_t MiB = 1u << 20;
  char* ws = (char*)d_ws;
  unsigned short* x_bf    = (unsigned short*)(ws + 0 * MiB);   // 8 MiB
  unsigned short* Wqkv_bf = (unsigned short*)(ws + 8 * MiB);   // 6 MiB (Wq|Wk|Wv rows)
  unsigned short* Wo_bf   = (unsigned short*)(ws + 14 * MiB);  // 2 MiB
  unsigned short* W1_bf   = (unsigned short*)(ws + 16 * MiB);
  unsigned short* W2_bf   = (unsigned short*)(ws + 18 * MiB);
  unsigned short* Q_bf    = (unsigned short*)(ws + 20 * MiB);  // 8 MiB
  unsigned short* K_bf    = (unsigned short*)(ws + 28 * MiB);  // 8 MiB
  unsigned short* Vt_bf   = (unsigned short*)(ws + 36 * MiB);  // 8 MiB (pre-transposed V)
  unsigned short* O_bf    = (unsigned short*)(ws + 44 * MiB);  // 8 MiB
  float*          attnpr  = (float*)(ws + 52 * MiB);           // 16 MiB
  float*          x1buf   = (float*)(ws + 68 * MiB);           // 16 MiB
  unsigned short* x1_bf   = (unsigned short*)(ws + 20 * MiB);  // reuse Q (dead)
  unsigned short* ff1_bf  = (unsigned short*)(ws + 28 * MiB);  // reuse K (dead)
  float*          ff2buf  = (float*)(ws + 36 * MiB);           // reuse V+O (dead)

  cvt_all<<<dim3(1024, 10), dim3(256), 0, stream>>>(
      x, Wq_w, Wk_w, Wv_w, Wo_w, W1_w, W2_w, x_bf, Wqkv_bf, Wo_bf, W1_bf, W2_bf);

  // fused QKV: C[4096,3072]; seg0->Q rm, seg1->K rm, seg2->V transposed
  gemm_bt<false, 2><<<dim3(M / 64, 24), dim3(256), 0, stream>>>(
      x_bf, Wqkv_bf, Wq_b, Wk_b, Wv_b, Q_bf, K_bf, Vt_bf, M, 3072, D);

  attn_kernel<<<dim3(B * 16, S / 64), dim3(256), 0, stream>>>(Q_bf, K_bf, Vt_bf, maskp, O_bf);

  gemm_bt<false, 0><<<dim3(M / 64, 8), dim3(256), 0, stream>>>(
      O_bf, Wo_bf, Wo_b, nullptr, nullptr, attnpr, nullptr, nullptr, M, D, D);
  norm_residual<true><<<dim3(M), dim3(256), 0, stream>>>(x, attnpr, alpha1, beta1, x1buf, x1_bf);
  gemm_bt<true, 1><<<dim3(M / 64, 8), dim3(256), 0, stream>>>(
      x1_bf, W1_bf, W1_b, nullptr, nullptr, ff1_bf, nullptr, nullptr, M, D, D);
  gemm_bt<false, 0><<<dim3(M / 64, 8), dim3(256), 0, stream>>>(
      ff1_bf, W2_bf, W2_b, nullptr, nullptr, ff2buf, nullptr, nullptr, M, D, D);
  norm_residual<false><<<dim3(M), dim3(256), 0, stream>>>(x1buf, ff2buf, alpha2, beta2,
                                                          (float*)d_out, nullptr);
}